// Round 8
// baseline (6460.500 us; speedup 1.0000x reference)
//
#include <hip/hip_runtime.h>

// LSTM decoder w/ Bahdanau attention, MI355X.
// Persistent grid-synchronized kernel, 256 blocks x 512 threads (1 block/CU).
// TWO grid barriers per step:
//   PA (blocks 0..63, block = batch b; others idle-poll): stage h[b] (bf16 hpk) ->
//       LDS fp32; out(t-1)=h@Wfc2^T; q=h@Wq2^T; energies tanh(q+keys2)*v over all 256
//       enc rows (keys2 from L2); den = in-block wave reduce; ctx = normalized in-block,
//       written ONCE as packed bf16 (plain sc1 stores - NO atomics, NO zeroing, NO den
//       exchange).
//   PB (block=(rg 0..63, bg 0..3)): MFMA gates GEMM M=16 x N=32 x K=1088 bf16 16x16x32;
//       weights = B-frags in VGPRs (hi+lo split); A-tile staged as pure uint copies
//       (x2pk | ctxp | hpk, all packed bf16); LSTM pointwise; h -> hpk bf16 only.
// Lessons:
// R1: __threadfence/acquire => buffer_wbl2/inv per op => 65us barriers. RELAXED
//     agent-scope (sc1) atomics for all cross-block mutable data.
// R4: single-counter barrier collapses; per-block fp32 weight re-reads thrash L2.
// R5: sc1 traffic is ~0.6us per MB/step; minimize bytes, never duplicate fp32.
// R6: VALU-loop GEMM is LDS-broadcast-bound -> MFMA with lane-distributed A-tile.
// R7: quarter-split attention costs 2 atomic-RT chains + fp32 ctx traffic ->
//     in-block attention (this round).

#define B 64
#define T 128
#define IN_DIM 64
#define TE 256
#define HID 512
#define ATTN 256
#define OUTD 64
#define G 256
#define BS 512

typedef __attribute__((ext_vector_type(8))) short short8;
typedef __attribute__((ext_vector_type(4))) float f32x4;

__device__ __forceinline__ float fast_exp(float x) {
  return __builtin_amdgcn_exp2f(x * 1.44269504f);
}
__device__ __forceinline__ float fast_tanh(float x) {
  float ax = fabsf(x);
  float z = __builtin_amdgcn_exp2f(ax * -2.885390082f);  // e^{-2|x|}
  float r = (1.f - z) * __builtin_amdgcn_rcpf(1.f + z);
  return copysignf(r, x);
}
__device__ __forceinline__ float fast_sig(float x) {
  float z = __builtin_amdgcn_exp2f(x * -1.44269504f);    // e^{-x}
  return __builtin_amdgcn_rcpf(1.f + z);
}
__device__ __forceinline__ float bflo(unsigned u) { return __uint_as_float(u << 16); }
__device__ __forceinline__ float bfhi(unsigned u) {
  return __uint_as_float(u & 0xffff0000u);
}
__device__ __forceinline__ unsigned f2bf(float f) {  // RNE bf16 bits
  unsigned u = __float_as_uint(f);
  return (u + 0x7fff + ((u >> 16) & 1)) >> 16;
}

// Relaxed agent-scope atomics: global_load/store ... sc1 (coherence point, no L2 flush).
__device__ __forceinline__ unsigned aldu(const unsigned* p) {
  return __hip_atomic_load(p, __ATOMIC_RELAXED, __HIP_MEMORY_SCOPE_AGENT);
}
__device__ __forceinline__ void astu(unsigned* p, unsigned v) {
  __hip_atomic_store(p, v, __ATOMIC_RELAXED, __HIP_MEMORY_SCOPE_AGENT);
}

// Flag-array barrier (R3/R6/R7-proven). Signed >= : 0xAA poison is negative.
__device__ __forceinline__ void gridbar(int* flags, int seq, int bid, int tid) {
  asm volatile("s_waitcnt vmcnt(0)" ::: "memory");
  __syncthreads();
  if (tid == 0)
    __hip_atomic_store(&flags[bid], seq, __ATOMIC_RELAXED, __HIP_MEMORY_SCOPE_AGENT);
  if (tid < G) {
    while (__hip_atomic_load(&flags[tid], __ATOMIC_RELAXED,
                             __HIP_MEMORY_SCOPE_AGENT) < seq) {
      __builtin_amdgcn_s_sleep(1);
    }
  }
  __syncthreads();
}

// fp32 -> bf16 (RNE)
__global__ void cvt_kernel(const float* __restrict__ src,
                           unsigned short* __restrict__ dst, int n) {
  for (int i = blockIdx.x * blockDim.x + threadIdx.x; i < n;
       i += gridDim.x * blockDim.x)
    dst[i] = (unsigned short)f2bf(src[i]);
}
// fp32 pairs -> packed bf16x2
__global__ void pack2_kernel(const float* __restrict__ src,
                             unsigned* __restrict__ dst, int n2) {
  for (int i = blockIdx.x * blockDim.x + threadIdx.x; i < n2;
       i += gridDim.x * blockDim.x)
    dst[i] = f2bf(src[2 * i]) | (f2bf(src[2 * i + 1]) << 16);
}

// ---- keys2[b][e][a] = bf16( sum_k enc[b][e][k] * Wk[a][k] ) ----
__global__ __launch_bounds__(256, 2) void keys_kernel(
    const float* __restrict__ enc, const float* __restrict__ Wk,
    unsigned short* __restrict__ keys2) {
  __shared__ float et[16][512];
  __shared__ float wk[32][256];
  const int tid = threadIdx.x;
  const int b = blockIdx.x >> 4;
  const int e0 = (blockIdx.x & 15) * 16;

  for (int p = 0; p < 8; ++p) {
    int i = p * 256 + tid;
    int e = i >> 7, kq = i & 127;
    float4 vv = *(const float4*)&enc[((size_t)(b * TE + e0 + e)) * HID + kq * 4];
    *(float4*)&et[e][kq * 4] = vv;
  }

  float acc[8][2];
  #pragma unroll
  for (int i = 0; i < 8; ++i) { acc[i][0] = 0.f; acc[i][1] = 0.f; }
  const int a0 = tid & 127;
  const int eh = (tid >> 7) * 8;

  for (int kc = 0; kc < 512; kc += 32) {
    __syncthreads();
    for (int p = 0; p < 8; ++p) {
      int i = p * 256 + tid;
      int a = i >> 3, j4 = (i & 7) * 4;
      float4 w4 = *(const float4*)&Wk[(size_t)a * HID + kc + j4];
      wk[j4 + 0][a] = w4.x; wk[j4 + 1][a] = w4.y;
      wk[j4 + 2][a] = w4.z; wk[j4 + 3][a] = w4.w;
    }
    __syncthreads();
    for (int k = 0; k < 32; ++k) {
      float w0 = wk[k][a0], w1 = wk[k][a0 + 128];
      #pragma unroll
      for (int i = 0; i < 8; ++i) {
        float ev = et[eh + i][kc + k];
        acc[i][0] = fmaf(ev, w0, acc[i][0]);
        acc[i][1] = fmaf(ev, w1, acc[i][1]);
      }
    }
  }
  #pragma unroll
  for (int i = 0; i < 8; ++i)
    #pragma unroll
    for (int h = 0; h < 2; ++h)
      keys2[((size_t)(b * TE + e0 + eh + i)) * ATTN + a0 + 128 * h] =
          (unsigned short)f2bf(acc[i][h]);
}

__global__ __launch_bounds__(BS, 2) void main_kernel(
    const float* __restrict__ v,
    const float* __restrict__ Wih, const float* __restrict__ Whh,
    const float* __restrict__ bih, const float* __restrict__ bhh,
    const float* __restrict__ bfc,
    const unsigned short* __restrict__ enc2, const unsigned short* __restrict__ keys2,
    const unsigned short* __restrict__ Wq2, const unsigned short* __restrict__ Wfc2,
    const unsigned* __restrict__ x2pk,
    float* cbuf, unsigned* ctxp, unsigned* hpk, int* flags, float* out) {
  const int bid = blockIdx.x, tid = threadIdx.x;
  const int rg = bid >> 2, bg = bid & 3;       // PB role
  const int lane = tid & 63, wv = tid >> 6;

  // LDS (~54 KB)
  __shared__ unsigned alds[34 * 256];   // 34.8 KB A-tile [kc][m 16][16 dw, xor-swizzled]
  __shared__ float pc[2 * 4 * 16 * 17]; // 8.7 KB mfma partials [nt][kq][m][n pad17]
  __shared__ float glds[16 * 33];       // gate values [m][r pad33]
  __shared__ float hsh[HID];            // PA: staged h[b] (fp32, from bf16)
  __shared__ float qsh[320];            // PA: q, swizzled idx r+(r>>2)
  __shared__ float lwsh[TE];            // PA: exp weights, all 256 rows
  __shared__ float2 csh2[512];          // PA: ctx partials [rh][cp]
  __shared__ float dsh[1];              // PA: rcp(den)
  __shared__ float blds[32];            // PB: biases

  // ---- prologue: persistent registers ----
  if (tid < 32) {
    const int gr2 = (tid >> 3) * 512 + rg * 8 + (tid & 7);
    blds[tid] = bih[gr2] + bhh[gr2];
  }
  const float4 vvf = *(const float4*)&v[lane * 4];
  // PB mfma geometry: wave = (nt = N-tile of 16 rows, kq = K-slice)
  const int mL = lane & 15, qL = lane >> 4;
  const int nt = wv >> 2, kq = wv & 3;
  const int kstart = (kq < 2) ? kq * 9 : 18 + (kq - 2) * 8;  // 9,9,8,8 chunks of K=32
  const int nch = (kq < 2) ? 9 : 8;
  const int aoff = mL * 16 + ((qL * 4) ^ (((mL >> 1) & 3) * 4));  // A-frag dword offset
  // B-fragments (weights) in VGPRs, step-invariant: hi + lo bf16 split
  short8 bh[9], bl[9];
  {
    const int rloc = nt * 16 + mL;  // row 0..31 of this block
    const int grow2 = (rloc >> 3) * 512 + rg * 8 + (rloc & 7);
    #pragma unroll
    for (int c = 0; c < 9; ++c) {
      unsigned uh[4] = {0, 0, 0, 0}, ul[4] = {0, 0, 0, 0};
      if (c < nch) {
        const int kc = kstart + c;
        #pragma unroll
        for (int j = 0; j < 8; ++j) {
          const int k = kc * 32 + qL * 8 + j;
          const float w = (k < 576) ? Wih[(size_t)grow2 * 576 + k]
                                    : Whh[(size_t)grow2 * 512 + (k - 576)];
          const unsigned hi = f2bf(w);
          const float lo = w - __uint_as_float(hi << 16);
          uh[j >> 1] |= hi << (16 * (j & 1));
          ul[j >> 1] |= f2bf(lo) << (16 * (j & 1));
        }
      }
      uint4 th; th.x = uh[0]; th.y = uh[1]; th.z = uh[2]; th.w = uh[3];
      uint4 tl; tl.x = ul[0]; tl.y = ul[1]; tl.z = ul[2]; tl.w = ul[3];
      bh[c] = __builtin_bit_cast(short8, th);
      bl[c] = __builtin_bit_cast(short8, tl);
    }
  }

  int seq = 0;

  for (int t = 0; t < T; ++t) {
    // ================= PA: full attention in-block (blocks 0..63) =================
    if (bid < B) {
      const int b = bid;
      // stage h[b]: 256 packed bf16 dwords -> 512 fp32
      if (tid < 256) {
        unsigned u = aldu(hpk + (size_t)(t & 1) * B * 256 + b * 256 + tid);
        hsh[2 * tid] = bflo(u);
        hsh[2 * tid + 1] = bfhi(u);
      }
      __syncthreads();
      if (t >= 1) {  // out(t-1) = h @ Wfc2^T + bfc, rotated k-chunks
        const int o = tid >> 3, c = tid & 7;
        const unsigned short* wr = Wfc2 + (size_t)o * HID;
        float oa = 0.f;
        #pragma unroll
        for (int j = 0; j < 8; ++j) {
          const int jj = c * 64 + ((j + c) & 7) * 8;
          uint4 w8 = *(const uint4*)(wr + jj);
          const float* hp = &hsh[jj];
          oa = fmaf(bflo(w8.x), hp[0], oa); oa = fmaf(bfhi(w8.x), hp[1], oa);
          oa = fmaf(bflo(w8.y), hp[2], oa); oa = fmaf(bfhi(w8.y), hp[3], oa);
          oa = fmaf(bflo(w8.z), hp[4], oa); oa = fmaf(bfhi(w8.z), hp[5], oa);
          oa = fmaf(bflo(w8.w), hp[6], oa); oa = fmaf(bfhi(w8.w), hp[7], oa);
        }
        oa += __shfl_xor(oa, 1, 64); oa += __shfl_xor(oa, 2, 64);
        oa += __shfl_xor(oa, 4, 64);
        if (c == 0) out[((size_t)b * T + (t - 1)) * OUTD + o] = oa + bfc[o];
      }
      {  // q[256] = h @ Wq2^T: 2 threads/row
        const int r = tid >> 1, c2 = tid & 1;
        const unsigned short* wr = Wq2 + (size_t)r * HID + c2 * 256;
        const float* hb = &hsh[c2 * 256];
        float qa = 0.f;
        #pragma unroll 8
        for (int j = 0; j < 32; ++j) {
          uint4 w8 = ((const uint4*)wr)[j];
          const float* hp = hb + j * 8;
          qa = fmaf(bflo(w8.x), hp[0], qa); qa = fmaf(bfhi(w8.x), hp[1], qa);
          qa = fmaf(bflo(w8.y), hp[2], qa); qa = fmaf(bfhi(w8.y), hp[3], qa);
          qa = fmaf(bflo(w8.z), hp[4], qa); qa = fmaf(bfhi(w8.z), hp[5], qa);
          qa = fmaf(bflo(w8.w), hp[6], qa); qa = fmaf(bfhi(w8.w), hp[7], qa);
        }
        qa += __shfl_xor(qa, 1, 64);
        if (c2 == 0) qsh[r + (r >> 2)] = qa;
      }
      __syncthreads();
      {  // energies for all 256 rows: wave wv owns rows wv*32..+32
        float q4[4];
        #pragma unroll
        for (int j = 0; j < 4; ++j) q4[j] = qsh[5 * lane + j];
        const unsigned* kb = (const unsigned*)keys2 + (size_t)b * TE * 128 + lane * 2;
        #pragma unroll 4
        for (int i = 0; i < 32; ++i) {
          const int row = wv * 32 + i;
          uint2 k4 = *(const uint2*)(kb + (size_t)row * 128);
          float p = fast_tanh(q4[0] + bflo(k4.x)) * vvf.x;
          p = fmaf(fast_tanh(q4[1] + bfhi(k4.x)), vvf.y, p);
          p = fmaf(fast_tanh(q4[2] + bflo(k4.y)), vvf.z, p);
          p = fmaf(fast_tanh(q4[3] + bfhi(k4.y)), vvf.w, p);
          #pragma unroll
          for (int m = 1; m < 64; m <<= 1) p += __shfl_xor(p, m, 64);
          if (lane == 0) lwsh[row] = fast_exp(p);
        }
      }
      __syncthreads();
      if (tid < 64) {  // den: in-block wave reduce, no cross-block exchange
        float p = (lwsh[tid] + lwsh[tid + 64]) + (lwsh[tid + 128] + lwsh[tid + 192]);
        #pragma unroll
        for (int m = 1; m < 64; m <<= 1) p += __shfl_xor(p, m, 64);
        if (tid == 0) dsh[0] = __builtin_amdgcn_rcpf(p);
      }
      {  // ctx over all 256 rows: thread (cp = col-pair, rh = row-half)
        const int cp = tid & 255, rh = tid >> 8;
        const unsigned* erow =
            (const unsigned*)enc2 + ((size_t)b * TE + rh * 128) * 256 + cp;
        const float* lwp = &lwsh[rh * 128];
        float a0 = 0.f, a1 = 0.f, b0 = 0.f, b1 = 0.f;
        #pragma unroll 8
        for (int e = 0; e < 128; e += 2) {
          float lw0 = lwp[e], lw1 = lwp[e + 1];
          unsigned u0 = erow[(size_t)e * 256], u1 = erow[(size_t)(e + 1) * 256];
          a0 = fmaf(lw0, bflo(u0), a0); a1 = fmaf(lw0, bfhi(u0), a1);
          b0 = fmaf(lw1, bflo(u1), b0); b1 = fmaf(lw1, bfhi(u1), b1);
        }
        csh2[rh * 256 + cp] = make_float2(a0 + b0, a1 + b1);
      }
      __syncthreads();
      if (tid < 256) {  // normalize + pack + single sc1 store (no atomics!)
        const float li = dsh[0];
        float2 s0 = csh2[tid], s1 = csh2[256 + tid];
        astu(&ctxp[b * 256 + tid],
             f2bf((s0.x + s1.x) * li) | (f2bf((s0.y + s1.y) * li) << 16));
      }
    }
    ++seq; gridbar(flags, seq, bid, tid);

    // ================= PB: MFMA gates + LSTM update =================
    {
      const unsigned* hpkc = hpk + (size_t)(t & 1) * B * 256;
      // ---- stage A-tile: pure uint copies (all packed bf16) ----
      {
        const int sm = tid >> 5, ss = tid & 31;
        const int bgl = bg * 16 + sm;
        const int swm = ((sm >> 1) & 3) * 4;
        const int dcol = (ss & 15) ^ swm;
        alds[(ss >> 4) * 256 + sm * 16 + dcol] = x2pk[((size_t)bgl * T + t) * 32 + ss];
        #pragma unroll
        for (int p = 1; p <= 8; ++p) {  // ctx (normalized bf16)
          const int i = ss + 32 * p;
          alds[(i >> 4) * 256 + sm * 16 + dcol] = aldu(ctxp + bgl * 256 + (i - 32));
        }
        #pragma unroll
        for (int p = 9; p <= 16; ++p) {  // h (bf16)
          const int i = ss + 32 * p;
          alds[(i >> 4) * 256 + sm * 16 + dcol] =
              aldu(hpkc + (size_t)bgl * 256 + (i - 288));
        }
      }
      __syncthreads();
      // ---- MFMA: 8-9 chunks, hi+lo weight split ----
      {
        f32x4 ach = {0.f, 0.f, 0.f, 0.f}, acl = {0.f, 0.f, 0.f, 0.f};
        #pragma unroll
        for (int c = 0; c < 9; ++c) {
          if (c < nch) {
            const uint4 av = *(const uint4*)&alds[(kstart + c) * 256 + aoff];
            const short8 a8 = __builtin_bit_cast(short8, av);
            ach = __builtin_amdgcn_mfma_f32_16x16x32_bf16(a8, bh[c], ach, 0, 0, 0);
            acl = __builtin_amdgcn_mfma_f32_16x16x32_bf16(a8, bl[c], acl, 0, 0, 0);
          }
        }
        #pragma unroll
        for (int rr = 0; rr < 4; ++rr)
          pc[((nt * 4 + kq) * 16 + qL * 4 + rr) * 17 + mL] = ach[rr] + acl[rr];
      }
      __syncthreads();
      {  // reduce 4 K-slices + bias -> glds[m][r]
        const int r2 = tid >> 4, mb = tid & 15;
        const int pbase = ((r2 >> 4) * 64 + mb) * 17 + (r2 & 15);
        float s = blds[r2] + ((pc[pbase] + pc[pbase + 272]) +
                              (pc[pbase + 544] + pc[pbase + 816]));
        glds[mb * 33 + r2] = s;
      }
      __syncthreads();
      if (tid < 128) {  // pointwise LSTM; h -> hpk bf16 only
        const int bbl = tid >> 3, hl = tid & 7;
        const int bb2 = bg * 16 + bbl, hu = rg * 8 + hl;
        const float gi = glds[bbl * 33 + hl],      gf = glds[bbl * 33 + 8 + hl];
        const float gg = glds[bbl * 33 + 16 + hl], go = glds[bbl * 33 + 24 + hl];
        const float cold = cbuf[bb2 * HID + hu];  // block-private: plain cached ok
        const float cn = fast_sig(gf) * cold + fast_sig(gi) * fast_tanh(gg);
        const float hn = fast_sig(go) * fast_tanh(cn);
        cbuf[bb2 * HID + hu] = cn;
        const float ho = __shfl_xor(hn, 1, 64);
        if ((hl & 1) == 0)
          astu(hpk + (size_t)((t + 1) & 1) * B * 256 + bb2 * 256 + rg * 4 + (hl >> 1),
               f2bf(hn) | (f2bf(ho) << 16));
      }
    }
    ++seq; gridbar(flags, seq, bid, tid);
  }

  // ---------------- epilogue: out(127) from h_128 (hpk slot 0) ----------------
  if (bid < B) {
    const int b = bid;
    if (tid < 256) {
      unsigned u = aldu(hpk + b * 256 + tid);
      hsh[2 * tid] = bflo(u);
      hsh[2 * tid + 1] = bfhi(u);
    }
    __syncthreads();
    const int o = tid >> 3, c = tid & 7;
    const unsigned short* wr = Wfc2 + (size_t)o * HID;
    float oa = 0.f;
    #pragma unroll
    for (int j = 0; j < 8; ++j) {
      const int jj = c * 64 + ((j + c) & 7) * 8;
      uint4 w8 = *(const uint4*)(wr + jj);
      const float* hp = &hsh[jj];
      oa = fmaf(bflo(w8.x), hp[0], oa); oa = fmaf(bfhi(w8.x), hp[1], oa);
      oa = fmaf(bflo(w8.y), hp[2], oa); oa = fmaf(bfhi(w8.y), hp[3], oa);
      oa = fmaf(bflo(w8.z), hp[4], oa); oa = fmaf(bfhi(w8.z), hp[5], oa);
      oa = fmaf(bflo(w8.w), hp[6], oa); oa = fmaf(bfhi(w8.w), hp[7], oa);
    }
    oa += __shfl_xor(oa, 1, 64); oa += __shfl_xor(oa, 2, 64);
    oa += __shfl_xor(oa, 4, 64);
    if (c == 0) out[((size_t)b * T + 127) * OUTD + o] = oa + bfc[o];
  }
}

extern "C" void kernel_launch(void* const* d_in, const int* in_sizes, int n_in,
                              void* d_out, int out_size, void* d_ws, size_t ws_size,
                              hipStream_t stream) {
  const float* x   = (const float*)d_in[0];
  const float* enc = (const float*)d_in[1];
  const float* Wq  = (const float*)d_in[2];
  const float* Wk  = (const float*)d_in[3];
  const float* v   = (const float*)d_in[4];
  const float* Wih = (const float*)d_in[5];
  const float* Whh = (const float*)d_in[6];
  const float* bih = (const float*)d_in[7];
  const float* bhh = (const float*)d_in[8];
  const float* Wfc = (const float*)d_in[9];
  const float* bfc = (const float*)d_in[10];

  // ws layout (~28 MB)
  unsigned short* enc2  = (unsigned short*)d_ws;          // B*TE*HID bf16
  unsigned short* keys2 = enc2 + (size_t)B * TE * HID;    // B*TE*ATTN bf16
  unsigned short* Wq2   = keys2 + (size_t)B * TE * ATTN;  // ATTN*HID
  unsigned short* Wfc2  = Wq2 + ATTN * HID;               // OUTD*HID
  unsigned* x2pk = (unsigned*)(Wfc2 + OUTD * HID);        // B*T*32 packed bf16 x
  unsigned* ctxp = x2pk + (size_t)B * T * 32;             // B*256 packed bf16 ctx
  float* cbuf = (float*)(ctxp + B * 256);                 // B*HID fp32 (zeroed)
  unsigned* hpk = (unsigned*)(cbuf + B * HID);            // 2*B*256 packed bf16 h (dbuf)
  int* flags = (int*)(hpk + 2 * B * 256);                 // 256

  // zero cbuf|hpk|flags (contiguous) every call
  hipMemsetAsync(cbuf, 0, (size_t)(B * HID + 2 * B * 256 + 256) * 4, stream);

  cvt_kernel<<<dim3(512), dim3(256), 0, stream>>>(enc, enc2, B * TE * HID);
  cvt_kernel<<<dim3(64), dim3(256), 0, stream>>>(Wq, Wq2, ATTN * HID);
  cvt_kernel<<<dim3(32), dim3(256), 0, stream>>>(Wfc, Wfc2, OUTD * HID);
  pack2_kernel<<<dim3(128), dim3(256), 0, stream>>>(x, x2pk, B * T * 32);
  keys_kernel<<<dim3(1024), dim3(256), 0, stream>>>(enc, Wk, keys2);
  main_kernel<<<dim3(G), dim3(BS), 0, stream>>>(
      v, Wih, Whh, bih, bhh, bfc, enc2, keys2, Wq2, Wfc2, x2pk,
      cbuf, ctxp, hpk, flags, (float*)d_out);
}